// Round 4
// baseline (133.200 us; speedup 1.0000x reference)
//
#include <hip/hip_runtime.h>

#define CH 30
#define CELLS 49
#define ROW (CELLS * CH)   // 1470 floats per batch row
#define RPB 4              // rows per block, one wave per row

__device__ __forceinline__ float waveReduce(float v) {
    #pragma unroll
    for (int o = 32; o > 0; o >>= 1) v += __shfl_xor(v, o, 64);
    return v;
}

__global__ __launch_bounds__(256) void yolo_main(const float* __restrict__ pred,
                                                 const float* __restrict__ targ,
                                                 float* __restrict__ ws,
                                                 int B, int NB) {
    const int w = threadIdx.x >> 6;
    const int lane = threadIdx.x & 63;
    const int r = blockIdx.x * RPB + w;
    const bool rowOk = (r < B);

    __shared__ float spb[RPB][CELLS * 10];   // pred box channels (obj cells only)
    __shared__ float stb[RPB][CELLS * 10];   // targ box channels (obj cells only)
    __shared__ float4 boxS[RPB][2 * CELLS];  // pred boxes xyxy
    __shared__ int clist[RPB][CELLS];
    __shared__ float partial[RPB][3];

    const float* P = pred + (size_t)r * ROW;
    const float* T = targ + (size_t)r * ROW;

    // ---- phase 0: one scattered conf read -> obj mask (wave-held) ----
    bool isObj = false;
    if (rowOk && lane < CELLS) isObj = T[lane * CH + 4] > 0.f;
    const unsigned long long mask = __ballot(isObj);
    const int nObj = __popcll(mask);
    if (isObj) {
        const int pos = __popcll(mask & ((1ull << lane) - 1ull));
        clist[w][pos] = lane;
    }

    float cls = 0.f, objc = 0.f, coord = 0.f;

    // ---- phase 1: coalesced float2 stream of both rows; classify per element ----
    // j indexes float2 pairs; pairs never straddle a cell (30 even, pair starts even).
    if (rowOk) {
        const float2* P2 = (const float2*)P;
        const float2* T2 = (const float2*)T;
        for (int j = lane; j < ROW / 2; j += 64) {
            const float2 p = P2[j];
            const float2 t = T2[j];
            const int cell = j / 15;               // == (2j)/30, magic-mul
            const int ch0 = 2 * (j - cell * 15);   // even channel of the pair
            const bool obj = (mask >> cell) & 1ull;
            if (ch0 >= 10) {
                if (obj) {                          // class loss
                    const float dx = p.x - t.x, dy = p.y - t.y;
                    cls += dx * dx + dy * dy;
                }
            } else if (obj) {                       // box channels -> LDS
                *(float2*)&spb[w][cell * 10 + ch0] = p;
                *(float2*)&stb[w][cell * 10 + ch0] = t;
            } else {                                // noobj conf loss (x0.5 folded)
                if (ch0 == 4) objc += 0.5f * p.x * p.x;              // t.x == 0
                else if (ch0 == 8) { const float d = p.y - t.y; objc += 0.5f * d * d; }
            }
        }
    }
    __syncthreads();

    const int nBox = 2 * nObj;

    // ---- phase 2: masked pred boxes -> xyxy ----
    for (int e = lane; e < nBox; e += 64) {
        const int c = clist[w][e >> 1];
        const float* pb = &spb[w][c * 10 + (e & 1) * 5];
        const float cx = pb[0], cy = pb[1], bw = pb[2], bh = pb[3];
        boxS[w][e] = make_float4(cx - 0.5f * bw, cy - 0.5f * bh,
                                 cx + 0.5f * bw, cy + 0.5f * bh);
    }
    __syncthreads();

    // ---- phase 3: per masked target box: max IoU, coord/obj losses ----
    for (int e = lane; e < nBox; e += 64) {
        const int c = clist[w][e >> 1];
        const int bb = c * 10 + (e & 1) * 5;
        const float tcx = stb[w][bb], tcy = stb[w][bb + 1];
        const float tw = stb[w][bb + 2], th = stb[w][bb + 3];
        const float tx1 = tcx - 0.5f * tw, ty1 = tcy - 0.5f * th;
        const float tx2 = tcx + 0.5f * tw, ty2 = tcy + 0.5f * th;
        const float ta = (tx2 - tx1) * (ty2 - ty1);
        float maxiou = 0.f;
        for (int i = 0; i < nBox; ++i) {
            const float4 pb4 = boxS[w][i];          // broadcast read
            const float lx = fmaxf(pb4.x, tx1), ly = fmaxf(pb4.y, ty1);
            const float rx = fminf(pb4.z, tx2), ry = fminf(pb4.w, ty2);
            const float iw = fmaxf(rx - lx, 0.f), ih = fmaxf(ry - ly, 0.f);
            const float inter = iw * ih;
            const float pa = (pb4.z - pb4.x) * (pb4.w - pb4.y);
            const float un = pa + ta - inter;
            const float iou = inter / (un > 0.f ? un : 1.f);
            maxiou = fmaxf(maxiou, iou);
        }
        if (maxiou != 0.f) {                        // cmask
            const float dcx = spb[w][bb] - tcx, dcy = spb[w][bb + 1] - tcy;
            coord += dcx * dcx + dcy * dcy;
            const float dw = sqrtf(spb[w][bb + 2]) - sqrtf(tw);
            const float dh = sqrtf(spb[w][bb + 3]) - sqrtf(th);
            coord += dw * dw + dh * dh;
            const float dc = spb[w][bb + 4] - stb[w][bb + 4];
            objc += dc * dc;
        }
    }

    // ---- wave reduce, cross-wave via LDS, one partial triple per block ----
    cls = waveReduce(cls); objc = waveReduce(objc); coord = waveReduce(coord);
    if (lane == 0) { partial[w][0] = cls; partial[w][1] = objc; partial[w][2] = coord; }
    __syncthreads();
    if (threadIdx.x == 0) {
        float c = 0.f, o = 0.f, x = 0.f;
        #pragma unroll
        for (int i = 0; i < RPB; ++i) { c += partial[i][0]; o += partial[i][1]; x += partial[i][2]; }
        ws[blockIdx.x] = c;
        ws[NB + blockIdx.x] = o;
        ws[2 * NB + blockIdx.x] = x;
    }
}

__global__ __launch_bounds__(1024) void yolo_reduce(const float* __restrict__ ws,
                                                    float* __restrict__ out,
                                                    int NB, float invB) {
    const int tid = threadIdx.x;
    const int w = tid >> 6, lane = tid & 63;
    __shared__ float sred[16];
    __shared__ float sums[3];
    #pragma unroll
    for (int s = 0; s < 3; ++s) {
        float v = 0.f;
        for (int i = tid; i < NB; i += 1024) v += ws[s * NB + i];
        v = waveReduce(v);
        if (lane == 0) sred[w] = v;
        __syncthreads();
        if (tid == 0) {
            float t = 0.f;
            #pragma unroll
            for (int k = 0; k < 16; ++k) t += sred[k];
            sums[s] = t;
        }
        __syncthreads();
    }
    if (tid == 0) {
        const float bcls = sums[0] * invB;
        const float bobj = sums[1] * invB;          // noobj*0.5 folded upstream
        const float bcoord = sums[2] * 5.0f * invB; // COORD_LAMBDA
        out[0] = bcls + bobj + bcoord;
        out[1] = bcls;
        out[2] = bobj;
        out[3] = bcoord;
    }
}

extern "C" void kernel_launch(void* const* d_in, const int* in_sizes, int n_in,
                              void* d_out, int out_size, void* d_ws, size_t ws_size,
                              hipStream_t stream) {
    const float* pred = (const float*)d_in[0];
    const float* targ = (const float*)d_in[1];
    float* ws = (float*)d_ws;
    float* out = (float*)d_out;
    const int B = in_sizes[0] / ROW;
    const int NB = (B + RPB - 1) / RPB;

    yolo_main<<<NB, 256, 0, stream>>>(pred, targ, ws, B, NB);
    yolo_reduce<<<1, 1024, 0, stream>>>(ws, out, NB, 1.0f / (float)B);
}

// Round 5
// 127.017 us; speedup vs baseline: 1.0487x; 1.0487x over previous
//
#include <hip/hip_runtime.h>

#define CH 30
#define CELLS 49
#define ROW 1470           // 49*30 floats per batch row
#define RPB 4              // rows per block, one wave per row
#define NPAIR 735          // ROW/2 float2 pairs
#define HALF 6             // unroll batch (2 batches of 6 -> 12 iterations)

__device__ __forceinline__ float waveReduce(float v) {
    #pragma unroll
    for (int o = 32; o > 0; o >>= 1) v += __shfl_xor(v, o, 64);
    return v;
}

__global__ __launch_bounds__(256) void yolo_main(const float* __restrict__ pred,
                                                 const float* __restrict__ targ,
                                                 float* __restrict__ ws, int B) {
    const int w = threadIdx.x >> 6;
    const int lane = threadIdx.x & 63;
    const int r = blockIdx.x * RPB + w;
    const bool rowOk = (r < B);

    __shared__ float4 boxS[RPB][2 * CELLS];  // pred boxes xyxy (broadcast reads)
    __shared__ int clist[RPB][CELLS];

    const float* P = pred + (size_t)r * ROW;
    const float* T = targ + (size_t)r * ROW;

    // ---- obj mask: one scattered conf read (lines are needed later anyway) ----
    bool isObj = rowOk && (lane < CELLS) && (T[lane * CH + 4] > 0.f);
    const unsigned long long mask = __ballot(isObj);
    const int nObj = __popcll(mask);
    if (isObj) {
        const int pos = __popcll(mask & ((1ull << lane) - 1ull));
        clist[w][pos] = lane;
    }

    float cls = 0.f, objc = 0.f, coord = 0.f;

    // ---- branch-free coalesced stream: all loads hoisted per half-batch ----
    const float2* P2 = (const float2*)P;
    const float2* T2 = (const float2*)T;
    if (rowOk) {
        #pragma unroll
        for (int h = 0; h < 2; ++h) {
            float2 pv[HALF], tv[HALF];
            #pragma unroll
            for (int it = 0; it < HALF; ++it) {
                const int j = lane + (h * HALF + it) * 64;
                const int jc = j < NPAIR ? j : NPAIR - 1;   // clamp, gate below
                pv[it] = P2[jc];
                tv[it] = T2[jc];
            }
            #pragma unroll
            for (int it = 0; it < HALF; ++it) {
                const int j = lane + (h * HALF + it) * 64;
                const bool valid = j < NPAIR;
                const int cell = (j * 17477) >> 18;          // j/15 for j<=767
                const int ch0 = 2 * (j - cell * 15);         // even channel of pair
                const float wobj = (float)((mask >> cell) & 1ull);
                const float dx = pv[it].x - tv[it].x;
                const float dy = pv[it].y - tv[it].y;
                const float ss = dx * dx + dy * dy;
                // class loss: channels 10..29, obj cells only
                cls += (valid && ch0 >= 10) ? wobj * ss : 0.f;
                // noobj conf loss (x0.5 folded): ch4 (.x of pair 4) + ch9 (.y of pair 8)
                const float nn = (ch0 == 4 ? dx * dx : 0.f) + (ch0 == 8 ? dy * dy : 0.f);
                objc += valid ? 0.5f * (1.f - wobj) * nn : 0.f;
            }
        }
    }
    __syncthreads();

    const int nBox = 2 * nObj;

    // ---- masked pred boxes -> xyxy in LDS (global reads are cache-warm) ----
    for (int e = lane; e < nBox; e += 64) {
        const int c = clist[w][e >> 1];
        const float* pb = P + c * CH + (e & 1) * 5;
        const float cx = pb[0], cy = pb[1], bw = pb[2], bh = pb[3];
        boxS[w][e] = make_float4(cx - 0.5f * bw, cy - 0.5f * bh,
                                 cx + 0.5f * bw, cy + 0.5f * bh);
    }
    __syncthreads();

    // ---- per masked target box: max IoU over masked pred boxes; losses ----
    for (int e = lane; e < nBox; e += 64) {
        const int c = clist[w][e >> 1];
        const float* tb = T + c * CH + (e & 1) * 5;
        const float tcx = tb[0], tcy = tb[1], tw = tb[2], th = tb[3];
        const float tx1 = tcx - 0.5f * tw, ty1 = tcy - 0.5f * th;
        const float tx2 = tcx + 0.5f * tw, ty2 = tcy + 0.5f * th;
        const float ta = (tx2 - tx1) * (ty2 - ty1);
        float maxiou = 0.f;
        for (int i = 0; i < nBox; ++i) {
            const float4 pb4 = boxS[w][i];          // wave-uniform addr = broadcast
            const float lx = fmaxf(pb4.x, tx1), ly = fmaxf(pb4.y, ty1);
            const float rx = fminf(pb4.z, tx2), ry = fminf(pb4.w, ty2);
            const float iw = fmaxf(rx - lx, 0.f), ih = fmaxf(ry - ly, 0.f);
            const float inter = iw * ih;
            const float pa = (pb4.z - pb4.x) * (pb4.w - pb4.y);
            const float un = pa + ta - inter;
            const float iou = inter / (un > 0.f ? un : 1.f);
            maxiou = fmaxf(maxiou, iou);
        }
        if (maxiou != 0.f) {                        // cmask
            const float* pb = P + c * CH + (e & 1) * 5;
            const float dcx = pb[0] - tcx, dcy = pb[1] - tcy;
            coord += dcx * dcx + dcy * dcy;
            const float dw = sqrtf(pb[2]) - sqrtf(tw);
            const float dh = sqrtf(pb[3]) - sqrtf(th);
            coord += dw * dw + dh * dh;
            const float dc = pb[4] - tb[4];
            objc += dc * dc;
        }
    }

    // ---- wave reduce; one partial triple per row ----
    cls = waveReduce(cls); objc = waveReduce(objc); coord = waveReduce(coord);
    if (rowOk && lane == 0) {
        ws[r] = cls;
        ws[B + r] = objc;
        ws[2 * B + r] = coord;
    }
}

__global__ __launch_bounds__(1024) void yolo_reduce(const float* __restrict__ ws,
                                                    float* __restrict__ out,
                                                    int B, float invB) {
    const int tid = threadIdx.x;
    const int w = tid >> 6, lane = tid & 63;
    __shared__ float sred[16];
    __shared__ float sums[3];
    #pragma unroll
    for (int s = 0; s < 3; ++s) {
        float v = 0.f;
        for (int i = tid; i < B; i += 1024) v += ws[s * B + i];
        v = waveReduce(v);
        if (lane == 0) sred[w] = v;
        __syncthreads();
        if (tid == 0) {
            float t = 0.f;
            #pragma unroll
            for (int k = 0; k < 16; ++k) t += sred[k];
            sums[s] = t;
        }
        __syncthreads();
    }
    if (tid == 0) {
        const float bcls = sums[0] * invB;
        const float bobj = sums[1] * invB;          // noobj*0.5 folded upstream
        const float bcoord = sums[2] * 5.0f * invB; // COORD_LAMBDA
        out[0] = bcls + bobj + bcoord;
        out[1] = bcls;
        out[2] = bobj;
        out[3] = bcoord;
    }
}

extern "C" void kernel_launch(void* const* d_in, const int* in_sizes, int n_in,
                              void* d_out, int out_size, void* d_ws, size_t ws_size,
                              hipStream_t stream) {
    const float* pred = (const float*)d_in[0];
    const float* targ = (const float*)d_in[1];
    float* ws = (float*)d_ws;
    float* out = (float*)d_out;
    const int B = in_sizes[0] / ROW;
    const int NB = (B + RPB - 1) / RPB;

    yolo_main<<<NB, 256, 0, stream>>>(pred, targ, ws, B);
    yolo_reduce<<<1, 1024, 0, stream>>>(ws, out, B, 1.0f / (float)B);
}

// Round 6
// 122.037 us; speedup vs baseline: 1.0915x; 1.0408x over previous
//
#include <hip/hip_runtime.h>

#define CH 30
#define CELLS 49
#define ROW 1470           // 49*30 floats per batch row
#define RPB 4              // rows per block, one wave per row
#define NPAIR 735          // ROW/2 float2 pairs
#define ITS 12             // ceil(735/64) pairs per lane, fully hoisted

__device__ __forceinline__ float waveReduce(float v) {
    #pragma unroll
    for (int o = 32; o > 0; o >>= 1) v += __shfl_xor(v, o, 64);
    return v;
}

// NOTE: no __syncthreads in this kernel. boxS/clist are per-wave slices ([w]);
// a wave executes in lockstep and the compiler inserts lgkmcnt waits for
// LDS write->read dependencies, so cross-wave barriers would only convoy.
__global__ __launch_bounds__(256) void yolo_main(const float* __restrict__ pred,
                                                 const float* __restrict__ targ,
                                                 float* __restrict__ ws, int B) {
    const int w = threadIdx.x >> 6;
    const int lane = threadIdx.x & 63;
    const int r = blockIdx.x * RPB + w;
    if (r >= B) return;                      // wave-uniform; no barriers below

    __shared__ float4 boxS[RPB][2 * CELLS];  // pred boxes xyxy (broadcast reads)
    __shared__ int clist[RPB][CELLS];

    const float* P = pred + (size_t)r * ROW;
    const float* T = targ + (size_t)r * ROW;
    const float2* P2 = (const float2*)P;
    const float2* T2 = (const float2*)T;

    // ---- issue conf load AND all 24 stream loads before any consumption ----
    const int cl = lane < CELLS ? lane : CELLS - 1;
    const float conf = T[cl * CH + 4];

    float2 pv[ITS], tv[ITS];
    #pragma unroll
    for (int it = 0; it < ITS; ++it) {
        const int j = lane + it * 64;
        const int jc = j < NPAIR ? j : NPAIR - 1;   // clamp, gate at consume
        pv[it] = P2[jc];
        tv[it] = T2[jc];
    }

    // ---- obj mask (waits only on the conf load) ----
    const bool isObj = (lane < CELLS) && (conf > 0.f);
    const unsigned long long mask = __ballot(isObj);
    const int nObj = __popcll(mask);
    if (isObj) clist[w][__popcll(mask & ((1ull << lane) - 1ull))] = lane;

    // ---- branch-free consume of the stream ----
    float cls = 0.f, objc = 0.f, coord = 0.f;
    #pragma unroll
    for (int it = 0; it < ITS; ++it) {
        const int j = lane + it * 64;
        const bool valid = j < NPAIR;
        const int cell = (j * 17477) >> 18;          // j/15 for j<=767
        const int ch0 = 2 * (j - cell * 15);         // even channel of the pair
        const float wobj = (float)((mask >> cell) & 1ull);
        const float dx = pv[it].x - tv[it].x;
        const float dy = pv[it].y - tv[it].y;
        // class loss: channels 10..29, obj cells only
        cls += (valid && ch0 >= 10) ? wobj * (dx * dx + dy * dy) : 0.f;
        // noobj conf loss (x0.5 folded): ch4 (.x of pair 4) + ch9 (.y of pair 8)
        const float nn = (ch0 == 4 ? dx * dx : 0.f) + (ch0 == 8 ? dy * dy : 0.f);
        objc += valid ? 0.5f * (1.f - wobj) * nn : 0.f;
    }

    const int nBox = 2 * nObj;

    // ---- masked pred boxes -> xyxy in LDS (global reads are L1-warm) ----
    for (int e = lane; e < nBox; e += 64) {
        const int c = clist[w][e >> 1];
        const float* pb = P + c * CH + (e & 1) * 5;
        const float cx = pb[0], cy = pb[1], bw = pb[2], bh = pb[3];
        boxS[w][e] = make_float4(cx - 0.5f * bw, cy - 0.5f * bh,
                                 cx + 0.5f * bw, cy + 0.5f * bh);
    }

    // ---- per masked target box: max IoU over masked pred boxes; losses ----
    for (int e = lane; e < nBox; e += 64) {
        const int c = clist[w][e >> 1];
        const float* tb = T + c * CH + (e & 1) * 5;
        const float tcx = tb[0], tcy = tb[1], tw = tb[2], th = tb[3];
        const float tx1 = tcx - 0.5f * tw, ty1 = tcy - 0.5f * th;
        const float tx2 = tcx + 0.5f * tw, ty2 = tcy + 0.5f * th;
        const float ta = (tx2 - tx1) * (ty2 - ty1);
        float maxiou = 0.f;
        for (int i = 0; i < nBox; ++i) {
            const float4 pb4 = boxS[w][i];          // wave-uniform addr = broadcast
            const float lx = fmaxf(pb4.x, tx1), ly = fmaxf(pb4.y, ty1);
            const float rx = fminf(pb4.z, tx2), ry = fminf(pb4.w, ty2);
            const float iw = fmaxf(rx - lx, 0.f), ih = fmaxf(ry - ly, 0.f);
            const float inter = iw * ih;
            const float pa = (pb4.z - pb4.x) * (pb4.w - pb4.y);
            const float un = pa + ta - inter;
            const float iou = inter / (un > 0.f ? un : 1.f);
            maxiou = fmaxf(maxiou, iou);
        }
        if (maxiou != 0.f) {                        // cmask
            const float* pb = P + c * CH + (e & 1) * 5;
            const float dcx = pb[0] - tcx, dcy = pb[1] - tcy;
            coord += dcx * dcx + dcy * dcy;
            const float dw = sqrtf(pb[2]) - sqrtf(tw);
            const float dh = sqrtf(pb[3]) - sqrtf(th);
            coord += dw * dw + dh * dh;
            const float dc = pb[4] - tb[4];
            objc += dc * dc;
        }
    }

    // ---- wave reduce; one partial triple per row ----
    cls = waveReduce(cls); objc = waveReduce(objc); coord = waveReduce(coord);
    if (lane == 0) {
        ws[r] = cls;
        ws[B + r] = objc;
        ws[2 * B + r] = coord;
    }
}

__global__ __launch_bounds__(1024) void yolo_reduce(const float* __restrict__ ws,
                                                    float* __restrict__ out,
                                                    int B, float invB) {
    const int tid = threadIdx.x;
    const int w = tid >> 6, lane = tid & 63;
    float c = 0.f, o = 0.f, x = 0.f;
    for (int i = tid; i < B; i += 1024) {
        c += ws[i];
        o += ws[B + i];
        x += ws[2 * B + i];
    }
    c = waveReduce(c); o = waveReduce(o); x = waveReduce(x);
    __shared__ float sred[16][3];
    if (lane == 0) { sred[w][0] = c; sred[w][1] = o; sred[w][2] = x; }
    __syncthreads();
    if (tid == 0) {
        float C = 0.f, O = 0.f, X = 0.f;
        #pragma unroll
        for (int k = 0; k < 16; ++k) { C += sred[k][0]; O += sred[k][1]; X += sred[k][2]; }
        const float bcls = C * invB;
        const float bobj = O * invB;          // noobj*0.5 folded upstream
        const float bcoord = X * 5.0f * invB; // COORD_LAMBDA
        out[0] = bcls + bobj + bcoord;
        out[1] = bcls;
        out[2] = bobj;
        out[3] = bcoord;
    }
}

extern "C" void kernel_launch(void* const* d_in, const int* in_sizes, int n_in,
                              void* d_out, int out_size, void* d_ws, size_t ws_size,
                              hipStream_t stream) {
    const float* pred = (const float*)d_in[0];
    const float* targ = (const float*)d_in[1];
    float* ws = (float*)d_ws;
    float* out = (float*)d_out;
    const int B = in_sizes[0] / ROW;
    const int NB = (B + RPB - 1) / RPB;

    yolo_main<<<NB, 256, 0, stream>>>(pred, targ, ws, B);
    yolo_reduce<<<1, 1024, 0, stream>>>(ws, out, B, 1.0f / (float)B);
}